// Round 7
// baseline (3649.817 us; speedup 1.0000x reference)
//
#include <hip/hip_runtime.h>
#include <math.h>

#define BB 64   // batch
#define TT 64   // time steps
#define NN 512  // nodes
#define HH 32   // hidden
#define CC 33   // C_IN + H
#define EE 10   // embed dim
#define GG 128  // 4*H
#define COLS 2112 // B*H + B  (h columns + x columns)

// ---------------- prologue kernels ----------------

// A = softmax(relu(E E^T), axis=1) * mask ; one block per row n
__global__ __launch_bounds__(256) void k_A(const float* __restrict__ E,
                                           const float* __restrict__ mask,
                                           float* __restrict__ A) {
  __shared__ float sE[NN * EE];
  __shared__ float red[256];
  int tid = threadIdx.x, n = blockIdx.x;
  for (int i = tid; i < NN * EE; i += 256) sE[i] = E[i];
  __syncthreads();
  float en[EE];
#pragma unroll
  for (int d = 0; d < EE; ++d) en[d] = sE[n * EE + d];
  float sv[2];
  float mx = -1e30f;
#pragma unroll
  for (int r = 0; r < 2; ++r) {
    int m = tid + r * 256;
    float s = 0.f;
#pragma unroll
    for (int d = 0; d < EE; ++d) s += en[d] * sE[m * EE + d];
    s = fmaxf(s, 0.f);
    sv[r] = s;
    mx = fmaxf(mx, s);
  }
  red[tid] = mx; __syncthreads();
  for (int s = 128; s > 0; s >>= 1) {
    if (tid < s) red[tid] = fmaxf(red[tid], red[tid + s]);
    __syncthreads();
  }
  mx = red[0]; __syncthreads();
  float sum = 0.f;
#pragma unroll
  for (int r = 0; r < 2; ++r) { sv[r] = expf(sv[r] - mx); sum += sv[r]; }
  red[tid] = sum; __syncthreads();
  for (int s = 128; s > 0; s >>= 1) {
    if (tid < s) red[tid] += red[tid + s];
    __syncthreads();
  }
  float inv = 1.f / red[0];
#pragma unroll
  for (int r = 0; r < 2; ++r) {
    int m = tid + r * 256;
    A[n * NN + m] = sv[r] * inv * mask[n * NN + m];
  }
}

// per-node weights / bias: W[n,k,c,o] = sum_d E[n,d]*Wp[d,k,c,o]; bias[n,o]
__global__ __launch_bounds__(256) void k_Wb(const float* __restrict__ E,
                                            const float* __restrict__ Wp,
                                            const float* __restrict__ bp,
                                            float* __restrict__ W,
                                            float* __restrict__ bias) {
  int tid = threadIdx.x, n = blockIdx.x;
  float e[EE];
#pragma unroll
  for (int d = 0; d < EE; ++d) e[d] = E[n * EE + d];
  for (int i = tid; i < 2 * CC * GG; i += 256) {
    float acc = 0.f;
#pragma unroll
    for (int d = 0; d < EE; ++d) acc += e[d] * Wp[d * (2 * CC * GG) + i];
    W[n * (2 * CC * GG) + i] = acc;
  }
  if (tid < GG) {
    float acc = 0.f;
#pragma unroll
    for (int d = 0; d < EE; ++d) acc += e[d] * bp[d * GG + tid];
    bias[n * GG + tid] = acc;
  }
}

// XT[t][m][b] = x[b][t][m]  (tiled transpose)
__global__ __launch_bounds__(256) void k_xt(const float* __restrict__ x,
                                            float* __restrict__ xt) {
  __shared__ float tile[64][65];
  int tid = threadIdx.x;
  int t = blockIdx.x >> 3, m0 = (blockIdx.x & 7) << 6;
  int l16 = tid & 15, grp = tid >> 4;
#pragma unroll
  for (int r = 0; r < 4; ++r) {
    int b = r * 16 + grp;
    float4 v = *reinterpret_cast<const float4*>(&x[(b * TT + t) * NN + m0 + l16 * 4]);
    tile[b][l16 * 4 + 0] = v.x; tile[b][l16 * 4 + 1] = v.y;
    tile[b][l16 * 4 + 2] = v.z; tile[b][l16 * 4 + 3] = v.w;
  }
  __syncthreads();
#pragma unroll
  for (int r = 0; r < 4; ++r) {
    int m = r * 16 + grp;
    float4 v;
    v.x = tile[l16 * 4 + 0][m]; v.y = tile[l16 * 4 + 1][m];
    v.z = tile[l16 * 4 + 2][m]; v.w = tile[l16 * 4 + 3][m];
    *reinterpret_cast<float4*>(&xt[(t * NN + m0 + m) * BB + l16 * 4]) = v;
  }
}

// h/c init from init_state; h stored [n][b][hh]
__global__ __launch_bounds__(256) void k_init(const float* __restrict__ init,
                                              float* __restrict__ h,
                                              float* __restrict__ c) {
  int i = blockIdx.x * 256 + threadIdx.x;
  if (i >= NN * BB * HH) return;
  int n = i >> 11, r = i & 2047, b = r >> 5, hh = r & 31;
  h[i] = init[((b * 2 + 0) * NN + n) * HH + hh];
  c[i] = init[((b * 2 + 1) * NN + n) * HH + hh];
}

// ---------------- per-step kernels ----------------

// az[n][j] = sum_m A[n][m] * B[m][j];  B = [ h(512x2048) | XT_t(512x64) ]
// BK=32 staging (half the barriers of round 1); per-thread k-ascending
// accumulation order identical to round 1 -> bit-identical az.
__global__ __launch_bounds__(256) void k_gemm(const float* __restrict__ A,
                                              const float* __restrict__ h,
                                              const float* __restrict__ xt,
                                              float* __restrict__ az, int t) {
  __shared__ float As[32][68];  // [kk][row]
  __shared__ float Bs[32][64];  // [kk][col]
  int tid = threadIdx.x;
  int j0 = blockIdx.x * 64;
  int n0 = blockIdx.y * 64;
  int tx = tid & 15, ty = tid >> 4;
  int arow = tid & 63;          // A stage: row, 2 k-quads per thread
  int akq = tid >> 6;           // 0..3 ; second quad akq+4
  int bcol4 = tid & 15;         // B stage: col quad
  int brow0 = tid >> 4;         // 0..15 ; second row brow0+16
  const bool xtile = (j0 >= BB * HH);
  float acc[4][4] = {};
  for (int k0 = 0; k0 < NN; k0 += 32) {
#pragma unroll
    for (int p = 0; p < 2; ++p) {
      int kq = akq + p * 4;
      float4 a4 = *reinterpret_cast<const float4*>(&A[(n0 + arow) * NN + k0 + kq * 4]);
      As[kq * 4 + 0][arow] = a4.x; As[kq * 4 + 1][arow] = a4.y;
      As[kq * 4 + 2][arow] = a4.z; As[kq * 4 + 3][arow] = a4.w;
    }
#pragma unroll
    for (int p = 0; p < 2; ++p) {
      int brow = brow0 + p * 16;
      float4 b4;
      if (!xtile)
        b4 = *reinterpret_cast<const float4*>(&h[(k0 + brow) * (BB * HH) + j0 + bcol4 * 4]);
      else
        b4 = *reinterpret_cast<const float4*>(&xt[(t * NN + k0 + brow) * BB + (j0 - BB * HH) + bcol4 * 4]);
      *reinterpret_cast<float4*>(&Bs[brow][bcol4 * 4]) = b4;
    }
    __syncthreads();
#pragma unroll
    for (int kk = 0; kk < 32; ++kk) {
      float4 av = *reinterpret_cast<const float4*>(&As[kk][ty * 4]);
      float4 bv = *reinterpret_cast<const float4*>(&Bs[kk][tx * 4]);
      float a[4] = {av.x, av.y, av.z, av.w};
      float b[4] = {bv.x, bv.y, bv.z, bv.w};
#pragma unroll
      for (int i = 0; i < 4; ++i)
#pragma unroll
        for (int j = 0; j < 4; ++j) acc[i][j] += a[i] * b[j];
    }
    __syncthreads();
  }
#pragma unroll
  for (int i = 0; i < 4; ++i) {
    float4 v = {acc[i][0], acc[i][1], acc[i][2], acc[i][3]};
    *reinterpret_cast<float4*>(&az[(n0 + ty * 4 + i) * COLS + j0 + tx * 4]) = v;
  }
}

// gates + LSTM update; one block per node n  (byte-identical to round 1)
__global__ __launch_bounds__(256) void k_step(const float* __restrict__ xt,
                                              const float* __restrict__ W,
                                              const float* __restrict__ bias,
                                              const float* __restrict__ az,
                                              float* __restrict__ h,
                                              float* __restrict__ c,
                                              float* __restrict__ out, int t) {
  __shared__ float Wl[2 * CC * GG];  // 8448 floats; reused as gates[64][128] later
  __shared__ float zl[2 * CC * 68];  // [k*33+c][b], padded to 68
  int tid = threadIdx.x, n = blockIdx.x;
  const float4* Wg = reinterpret_cast<const float4*>(&W[n * (2 * CC * GG)]);
  for (int i = tid; i < (2 * CC * GG) / 4; i += 256)
    *reinterpret_cast<float4*>(&Wl[i * 4]) = Wg[i];
  for (int i = tid; i < BB * HH; i += 256) {
    int b = i >> 5, hh = i & 31;
    zl[(1 + hh) * 68 + b] = h[n * (BB * HH) + i];
    zl[(CC + 1 + hh) * 68 + b] = az[n * COLS + i];
  }
  if (tid < BB) {
    zl[0 * 68 + tid] = xt[(t * NN + n) * BB + tid];
    zl[CC * 68 + tid] = az[n * COLS + BB * HH + tid];
  }
  __syncthreads();
  int tx = tid & 31, tyb = tid >> 5;  // o0 = tx*4 ; b = tyb*8 + bb
  float acc[8][4];
  {
    float4 bv = *reinterpret_cast<const float4*>(&bias[n * GG + tx * 4]);
#pragma unroll
    for (int bb = 0; bb < 8; ++bb) {
      acc[bb][0] = bv.x; acc[bb][1] = bv.y; acc[bb][2] = bv.z; acc[bb][3] = bv.w;
    }
  }
  for (int k = 0; k < 2; ++k) {
    for (int cc = 0; cc < CC; ++cc) {
      float4 w4 = *reinterpret_cast<const float4*>(&Wl[(k * CC + cc) * GG + tx * 4]);
      float4 za = *reinterpret_cast<const float4*>(&zl[(k * CC + cc) * 68 + tyb * 8]);
      float4 zb = *reinterpret_cast<const float4*>(&zl[(k * CC + cc) * 68 + tyb * 8 + 4]);
      float zv[8] = {za.x, za.y, za.z, za.w, zb.x, zb.y, zb.z, zb.w};
      float wv[4] = {w4.x, w4.y, w4.z, w4.w};
#pragma unroll
      for (int bb = 0; bb < 8; ++bb)
#pragma unroll
        for (int j = 0; j < 4; ++j) acc[bb][j] += zv[bb] * wv[j];
    }
  }
  __syncthreads();  // all threads done reading Wl
  float* gl = Wl;   // alias: gates [64][128]
#pragma unroll
  for (int bb = 0; bb < 8; ++bb) {
    float4 v = {acc[bb][0], acc[bb][1], acc[bb][2], acc[bb][3]};
    *reinterpret_cast<float4*>(&gl[(tyb * 8 + bb) * GG + tx * 4]) = v;
  }
  __syncthreads();
  for (int i = tid; i < BB * HH; i += 256) {
    int b = i >> 5, hh = i & 31;
    float gi = gl[b * GG + hh];
    float gf = gl[b * GG + 32 + hh];
    float go = gl[b * GG + 64 + hh];
    float gg = gl[b * GG + 96 + hh];
    float cold = c[n * (BB * HH) + i];
    float si = 1.f / (1.f + expf(-gi));
    float sf = 1.f / (1.f + expf(-gf));
    float so = 1.f / (1.f + expf(-go));
    float cnew = sf * cold + si * tanhf(gg);
    float hnew = so * tanhf(cnew);
    c[n * (BB * HH) + i] = cnew;
    h[n * (BB * HH) + i] = hnew;
    out[((b * TT + t) * NN + n) * HH + hh] = hnew;
  }
}

extern "C" void kernel_launch(void* const* d_in, const int* in_sizes, int n_in,
                              void* d_out, int out_size, void* d_ws, size_t ws_size,
                              hipStream_t stream) {
  const float* x    = (const float*)d_in[0];
  const float* init = (const float*)d_in[1];
  const float* E    = (const float*)d_in[2];
  const float* mask = (const float*)d_in[3];
  const float* Wp   = (const float*)d_in[4];
  const float* bp   = (const float*)d_in[5];
  float* out = (float*)d_out;
  float* ws = (float*)d_ws;
  float* A    = ws;                      // round-1 layout, unchanged
  float* W    = A + NN * NN;
  float* bias = W + NN * 2 * CC * GG;
  float* xt   = bias + NN * GG;
  float* h    = xt + TT * NN * BB;
  float* c    = h + NN * BB * HH;
  float* az   = c + NN * BB * HH;

  k_A<<<NN, 256, 0, stream>>>(E, mask, A);
  k_Wb<<<NN, 256, 0, stream>>>(E, Wp, bp, W, bias);
  k_xt<<<TT * 8, 256, 0, stream>>>(x, xt);
  k_init<<<(NN * BB * HH + 255) / 256, 256, 0, stream>>>(init, h, c);
  for (int t = 0; t < TT; ++t) {
    k_gemm<<<dim3(33, 8), 256, 0, stream>>>(A, h, xt, az, t);
    k_step<<<NN, 256, 0, stream>>>(xt, W, bias, az, h, c, out, t);
  }
}

// Round 8
// 3179.308 us; speedup vs baseline: 1.1480x; 1.1480x over previous
//
#include <hip/hip_runtime.h>
#include <math.h>

#define BB 64   // batch
#define TT 64   // time steps
#define NN 512  // nodes
#define HH 32   // hidden
#define CC 33   // C_IN + H
#define EE 10   // embed dim
#define GG 128  // 4*H
#define COLS 2112 // B*H + B  (h columns + x columns)
#define AZS (NN * COLS)  // one az partial slice

// ---------------- prologue kernels ----------------

// A = softmax(relu(E E^T), axis=1) * mask ; one block per row n
__global__ __launch_bounds__(256) void k_A(const float* __restrict__ E,
                                           const float* __restrict__ mask,
                                           float* __restrict__ A) {
  __shared__ float sE[NN * EE];
  __shared__ float red[256];
  int tid = threadIdx.x, n = blockIdx.x;
  for (int i = tid; i < NN * EE; i += 256) sE[i] = E[i];
  __syncthreads();
  float en[EE];
#pragma unroll
  for (int d = 0; d < EE; ++d) en[d] = sE[n * EE + d];
  float sv[2];
  float mx = -1e30f;
#pragma unroll
  for (int r = 0; r < 2; ++r) {
    int m = tid + r * 256;
    float s = 0.f;
#pragma unroll
    for (int d = 0; d < EE; ++d) s += en[d] * sE[m * EE + d];
    s = fmaxf(s, 0.f);
    sv[r] = s;
    mx = fmaxf(mx, s);
  }
  red[tid] = mx; __syncthreads();
  for (int s = 128; s > 0; s >>= 1) {
    if (tid < s) red[tid] = fmaxf(red[tid], red[tid + s]);
    __syncthreads();
  }
  mx = red[0]; __syncthreads();
  float sum = 0.f;
#pragma unroll
  for (int r = 0; r < 2; ++r) { sv[r] = expf(sv[r] - mx); sum += sv[r]; }
  red[tid] = sum; __syncthreads();
  for (int s = 128; s > 0; s >>= 1) {
    if (tid < s) red[tid] += red[tid + s];
    __syncthreads();
  }
  float inv = 1.f / red[0];
#pragma unroll
  for (int r = 0; r < 2; ++r) {
    int m = tid + r * 256;
    A[n * NN + m] = sv[r] * inv * mask[n * NN + m];
  }
}

// per-node weights / bias: W[n,k,c,o] = sum_d E[n,d]*Wp[d,k,c,o]; bias[n,o]
__global__ __launch_bounds__(256) void k_Wb(const float* __restrict__ E,
                                            const float* __restrict__ Wp,
                                            const float* __restrict__ bp,
                                            float* __restrict__ W,
                                            float* __restrict__ bias) {
  int tid = threadIdx.x, n = blockIdx.x;
  float e[EE];
#pragma unroll
  for (int d = 0; d < EE; ++d) e[d] = E[n * EE + d];
  for (int i = tid; i < 2 * CC * GG; i += 256) {
    float acc = 0.f;
#pragma unroll
    for (int d = 0; d < EE; ++d) acc += e[d] * Wp[d * (2 * CC * GG) + i];
    W[n * (2 * CC * GG) + i] = acc;
  }
  if (tid < GG) {
    float acc = 0.f;
#pragma unroll
    for (int d = 0; d < EE; ++d) acc += e[d] * bp[d * GG + tid];
    bias[n * GG + tid] = acc;
  }
}

// XT[t][m][b] = x[b][t][m]  (tiled transpose)
__global__ __launch_bounds__(256) void k_xt(const float* __restrict__ x,
                                            float* __restrict__ xt) {
  __shared__ float tile[64][65];
  int tid = threadIdx.x;
  int t = blockIdx.x >> 3, m0 = (blockIdx.x & 7) << 6;
  int l16 = tid & 15, grp = tid >> 4;
#pragma unroll
  for (int r = 0; r < 4; ++r) {
    int b = r * 16 + grp;
    float4 v = *reinterpret_cast<const float4*>(&x[(b * TT + t) * NN + m0 + l16 * 4]);
    tile[b][l16 * 4 + 0] = v.x; tile[b][l16 * 4 + 1] = v.y;
    tile[b][l16 * 4 + 2] = v.z; tile[b][l16 * 4 + 3] = v.w;
  }
  __syncthreads();
#pragma unroll
  for (int r = 0; r < 4; ++r) {
    int m = r * 16 + grp;
    float4 v;
    v.x = tile[l16 * 4 + 0][m]; v.y = tile[l16 * 4 + 1][m];
    v.z = tile[l16 * 4 + 2][m]; v.w = tile[l16 * 4 + 3][m];
    *reinterpret_cast<float4*>(&xt[(t * NN + m0 + m) * BB + l16 * 4]) = v;
  }
}

// h/c init from init_state; h stored [n][b][hh]
__global__ __launch_bounds__(256) void k_init(const float* __restrict__ init,
                                              float* __restrict__ h,
                                              float* __restrict__ c) {
  int i = blockIdx.x * 256 + threadIdx.x;
  if (i >= NN * BB * HH) return;
  int n = i >> 11, r = i & 2047, b = r >> 5, hh = r & 31;
  h[i] = init[((b * 2 + 0) * NN + n) * HH + hh];
  c[i] = init[((b * 2 + 1) * NN + n) * HH + hh];
}

// ---------------- per-step kernels ----------------

// Split-K GEMM: azp[kz][n][j] = sum_{m in slice kz} A[n][m] * B[m][j]
// B = [ h(512x2048) | XT_t(512x64) ]. blockIdx.z = kz, slice len = NN/ks.
__global__ __launch_bounds__(256) void k_gemm(const float* __restrict__ A,
                                              const float* __restrict__ h,
                                              const float* __restrict__ xt,
                                              float* __restrict__ azp,
                                              int t, int ks) {
  __shared__ float As[32][68];  // [kk][row]
  __shared__ float Bs[32][64];  // [kk][col]
  int tid = threadIdx.x;
  int j0 = blockIdx.x * 64;
  int n0 = blockIdx.y * 64;
  int kz = blockIdx.z;
  int Klen = NN / ks;
  int kbase = kz * Klen;
  int tx = tid & 15, ty = tid >> 4;
  int arow = tid >> 2;            // 0..63
  int akc = (tid & 3) * 4;        // 4-float chunk; second at +16
  int bcol4 = tid & 15;
  int brow0 = tid >> 4;           // 0..15
  const bool xtile = (j0 >= BB * HH);
  float acc[4][4] = {};
  for (int k0 = kbase; k0 < kbase + Klen; k0 += 32) {
    // A stage, coalesced: 4 lanes cover 64B contiguous per row
    float4 a0 = *reinterpret_cast<const float4*>(&A[(n0 + arow) * NN + k0 + akc]);
    float4 a1 = *reinterpret_cast<const float4*>(&A[(n0 + arow) * NN + k0 + 16 + akc]);
    As[akc + 0][arow] = a0.x; As[akc + 1][arow] = a0.y;
    As[akc + 2][arow] = a0.z; As[akc + 3][arow] = a0.w;
    As[16 + akc + 0][arow] = a1.x; As[16 + akc + 1][arow] = a1.y;
    As[16 + akc + 2][arow] = a1.z; As[16 + akc + 3][arow] = a1.w;
#pragma unroll
    for (int p = 0; p < 2; ++p) {
      int brow = brow0 + p * 16;
      float4 b4;
      if (!xtile)
        b4 = *reinterpret_cast<const float4*>(&h[(k0 + brow) * (BB * HH) + j0 + bcol4 * 4]);
      else
        b4 = *reinterpret_cast<const float4*>(&xt[(t * NN + k0 + brow) * BB + (j0 - BB * HH) + bcol4 * 4]);
      *reinterpret_cast<float4*>(&Bs[brow][bcol4 * 4]) = b4;
    }
    __syncthreads();
#pragma unroll
    for (int kk = 0; kk < 32; ++kk) {
      float4 av = *reinterpret_cast<const float4*>(&As[kk][ty * 4]);
      float4 bv = *reinterpret_cast<const float4*>(&Bs[kk][tx * 4]);
      float a[4] = {av.x, av.y, av.z, av.w};
      float b[4] = {bv.x, bv.y, bv.z, bv.w};
#pragma unroll
      for (int i = 0; i < 4; ++i)
#pragma unroll
        for (int j = 0; j < 4; ++j) acc[i][j] += a[i] * b[j];
    }
    __syncthreads();
  }
  float* dst = azp + (size_t)kz * AZS;
#pragma unroll
  for (int i = 0; i < 4; ++i) {
    float4 v = {acc[i][0], acc[i][1], acc[i][2], acc[i][3]};
    *reinterpret_cast<float4*>(&dst[(n0 + ty * 4 + i) * COLS + j0 + tx * 4]) = v;
  }
}

// gates + LSTM update; one block per node n. Sums ks az partials while staging.
__global__ __launch_bounds__(256) void k_step(const float* __restrict__ xt,
                                              const float* __restrict__ W,
                                              const float* __restrict__ bias,
                                              const float* __restrict__ azp,
                                              float* __restrict__ h,
                                              float* __restrict__ c,
                                              float* __restrict__ out,
                                              int t, int ks) {
  __shared__ float Wl[2 * CC * GG];  // reused as gates[64][128] later
  __shared__ float zl[2 * CC * 68];  // [k*33+c][b], padded to 68
  int tid = threadIdx.x, n = blockIdx.x;
  const float4* Wg = reinterpret_cast<const float4*>(&W[n * (2 * CC * GG)]);
  for (int i = tid; i < (2 * CC * GG) / 4; i += 256)
    *reinterpret_cast<float4*>(&Wl[i * 4]) = Wg[i];
  for (int i = tid; i < BB * HH; i += 256) {
    int b = i >> 5, hh = i & 31;
    zl[(1 + hh) * 68 + b] = h[n * (BB * HH) + i];
    float s = azp[n * COLS + i];
    for (int kz = 1; kz < ks; ++kz) s += azp[(size_t)kz * AZS + n * COLS + i];
    zl[(CC + 1 + hh) * 68 + b] = s;
  }
  if (tid < BB) {
    zl[0 * 68 + tid] = xt[(t * NN + n) * BB + tid];
    float s = azp[n * COLS + BB * HH + tid];
    for (int kz = 1; kz < ks; ++kz) s += azp[(size_t)kz * AZS + n * COLS + BB * HH + tid];
    zl[CC * 68 + tid] = s;
  }
  __syncthreads();
  int tx = tid & 31, tyb = tid >> 5;  // o0 = tx*4 ; b = tyb*8 + bb
  float acc[8][4];
  {
    float4 bv = *reinterpret_cast<const float4*>(&bias[n * GG + tx * 4]);
#pragma unroll
    for (int bb = 0; bb < 8; ++bb) {
      acc[bb][0] = bv.x; acc[bb][1] = bv.y; acc[bb][2] = bv.z; acc[bb][3] = bv.w;
    }
  }
  for (int k = 0; k < 2; ++k) {
    for (int cc = 0; cc < CC; ++cc) {
      float4 w4 = *reinterpret_cast<const float4*>(&Wl[(k * CC + cc) * GG + tx * 4]);
      float4 za = *reinterpret_cast<const float4*>(&zl[(k * CC + cc) * 68 + tyb * 8]);
      float4 zb = *reinterpret_cast<const float4*>(&zl[(k * CC + cc) * 68 + tyb * 8 + 4]);
      float zv[8] = {za.x, za.y, za.z, za.w, zb.x, zb.y, zb.z, zb.w};
      float wv[4] = {w4.x, w4.y, w4.z, w4.w};
#pragma unroll
      for (int bb = 0; bb < 8; ++bb)
#pragma unroll
        for (int j = 0; j < 4; ++j) acc[bb][j] += zv[bb] * wv[j];
    }
  }
  __syncthreads();  // all threads done reading Wl
  float* gl = Wl;   // alias: gates [64][128]
#pragma unroll
  for (int bb = 0; bb < 8; ++bb) {
    float4 v = {acc[bb][0], acc[bb][1], acc[bb][2], acc[bb][3]};
    *reinterpret_cast<float4*>(&gl[(tyb * 8 + bb) * GG + tx * 4]) = v;
  }
  __syncthreads();
  for (int i = tid; i < BB * HH; i += 256) {
    int b = i >> 5, hh = i & 31;
    float gi = gl[b * GG + hh];
    float gf = gl[b * GG + 32 + hh];
    float go = gl[b * GG + 64 + hh];
    float gg = gl[b * GG + 96 + hh];
    float cold = c[n * (BB * HH) + i];
    float si = 1.f / (1.f + expf(-gi));
    float sf = 1.f / (1.f + expf(-gf));
    float so = 1.f / (1.f + expf(-go));
    float cnew = sf * cold + si * tanhf(gg);
    float hnew = so * tanhf(cnew);
    c[n * (BB * HH) + i] = cnew;
    h[n * (BB * HH) + i] = hnew;
    out[((b * TT + t) * NN + n) * HH + hh] = hnew;
  }
}

extern "C" void kernel_launch(void* const* d_in, const int* in_sizes, int n_in,
                              void* d_out, int out_size, void* d_ws, size_t ws_size,
                              hipStream_t stream) {
  const float* x    = (const float*)d_in[0];
  const float* init = (const float*)d_in[1];
  const float* E    = (const float*)d_in[2];
  const float* mask = (const float*)d_in[3];
  const float* Wp   = (const float*)d_in[4];
  const float* bp   = (const float*)d_in[5];
  float* out = (float*)d_out;
  float* ws = (float*)d_ws;
  float* A    = ws;
  float* W    = A + NN * NN;
  float* bias = W + NN * 2 * CC * GG;
  float* xt   = bias + NN * GG;
  float* h    = xt + TT * NN * BB;
  float* c    = h + NN * BB * HH;
  float* azp  = c + NN * BB * HH;

  // ws-gated split-K selection (deterministic: ws_size fixed per run)
  size_t base_bytes = (size_t)(azp - ws) * 4;
  int ks = 1;
  if (ws_size >= base_bytes + 4ull * AZS * 4) ks = 4;
  else if (ws_size >= base_bytes + 2ull * AZS * 4) ks = 2;

  k_A<<<NN, 256, 0, stream>>>(E, mask, A);
  k_Wb<<<NN, 256, 0, stream>>>(E, Wp, bp, W, bias);
  k_xt<<<TT * 8, 256, 0, stream>>>(x, xt);
  k_init<<<(NN * BB * HH + 255) / 256, 256, 0, stream>>>(init, h, c);
  for (int t = 0; t < TT; ++t) {
    k_gemm<<<dim3(33, 8, ks), 256, 0, stream>>>(A, h, xt, azp, t, ks);
    k_step<<<NN, 256, 0, stream>>>(xt, W, bias, azp, h, c, out, t, ks);
  }
}